// Round 1
// baseline (1512.600 us; speedup 1.0000x reference)
//
#include <hip/hip_runtime.h>
#include <math.h>

#define NN 64
#define CC 64
#define TDIM 288
#define VV 19
#define DD 192
#define SS (TDIM*VV)        /* 5472 */
#define MSAMP (NN*SS)       /* 350208 samples for both batchnorms */

/* workspace layout (float offsets) */
#define WS_S    0           /* 64x64 second-moment sums           */
#define WS_MU   4096        /* 64 channel sums of x               */
#define WS_ZSUM 4160        /* 64 z sums                          */
#define WS_ZSS  4224        /* 64 z sum-of-squares                */
#define WS_BETA 4288        /* 192 folded bn0 shifts              */
#define WS_WP   4480        /* 64x192 folded weights W*rs0        */
#define WS_AP   16768       /* 3*8*19*19 normalized adjacency     */
#define WS_ZSC  25432       /* 64 final scale                     */
#define WS_ZSH  25496       /* 64 final shift                     */
#define WS_Z    25600       /* z tensor, 64*64*288*19 floats      */

/* ---------------- K1: second-moment matrix S = sum x x^T, and mu ---------- */
__global__ __launch_bounds__(256) void k1_cov(const float* __restrict__ x,
                                              float* __restrict__ ws) {
    __shared__ float X[64][68];     /* [sample][channel], padded for b128 */
    __shared__ float Lacc[4096];
    const int tid = threadIdx.x;
    const int n = blockIdx.y;
    const float* xb = x + (size_t)n * (CC * SS);

    float acc[8][8];
#pragma unroll
    for (int i = 0; i < 8; ++i)
#pragma unroll
        for (int l = 0; l < 8; ++l) acc[i][l] = 0.f;
    float mupart = 0.f;

    const int tile0 = blockIdx.x * 8;   /* 8 tiles of 64 samples per block */
    for (int tile = tile0; tile < tile0 + 8; ++tile) {
        const int s0 = tile * 64;
        int rem = SS - s0; if (rem > 64) rem = 64;
        __syncthreads();
        if (rem > 0) {
#pragma unroll
            for (int rep = 0; rep < 16; ++rep) {
                const int f = rep * 256 + tid;
                const int c = f >> 6, j = f & 63;
                X[j][c] = (j < rem) ? xb[c * SS + s0 + j] : 0.f;
            }
        }
        __syncthreads();
        if (rem > 0) {
            const int tile_i = tid & 63;
            const int jq = tid >> 6;
            const int r0 = (tile_i >> 3) << 3;
            const int c0 = (tile_i & 7) << 3;
            const int jb = jq * 16;
            for (int j = jb; j < jb + 16; ++j) {
                const float4 aA = *(const float4*)&X[j][r0];
                const float4 aB = *(const float4*)&X[j][r0 + 4];
                const float4 bA = *(const float4*)&X[j][c0];
                const float4 bB = *(const float4*)&X[j][c0 + 4];
                const float av[8] = {aA.x,aA.y,aA.z,aA.w,aB.x,aB.y,aB.z,aB.w};
                const float bv[8] = {bA.x,bA.y,bA.z,bA.w,bB.x,bB.y,bB.z,bB.w};
#pragma unroll
                for (int i = 0; i < 8; ++i)
#pragma unroll
                    for (int l = 0; l < 8; ++l)
                        acc[i][l] = fmaf(av[i], bv[l], acc[i][l]);
            }
            if (tid < 64) {          /* mu partial over this tile */
                float m = 0.f;
                for (int j = 0; j < 64; ++j) m += X[j][tid];
                mupart += m;
            }
        }
    }

    /* block-level reduce of the 4 j-quarters, then one atomic per entry */
    for (int f = tid; f < 4096; f += 256) Lacc[f] = 0.f;
    __syncthreads();
    {
        const int tile_i = tid & 63;
        const int jq = tid >> 6;
        for (int p = 0; p < 4; ++p) {
            if (jq == p) {
#pragma unroll
                for (int i = 0; i < 8; ++i)
#pragma unroll
                    for (int l = 0; l < 8; ++l)
                        Lacc[(i * 8 + l) * 64 + tile_i] += acc[i][l];
            }
            __syncthreads();
        }
    }
    for (int f = tid; f < 4096; f += 256) {
        const int il = f >> 6, tile_i = f & 63;
        const int i = il >> 3, l = il & 7;
        const int r0 = (tile_i >> 3) << 3, c0 = (tile_i & 7) << 3;
        atomicAdd(&ws[WS_S + (r0 + i) * 64 + (c0 + l)], Lacc[f]);
    }
    if (tid < 64) atomicAdd(&ws[WS_MU + tid], mupart);
}

/* -------- K2: analytic bn0 stats -> folded weights; normalized adjacency -- */
__global__ __launch_bounds__(256) void k2_prep(const float* __restrict__ A,
                                               const float* __restrict__ W,
                                               const float* __restrict__ bias,
                                               float* __restrict__ ws) {
    const int tid = threadIdx.x;
    if (blockIdx.x == 3) {
        /* A'[k,g,v,w] = A / (sqrt(8*sum_g A^2) + 1e-4) */
        for (int f = tid; f < 3 * 19 * 19; f += 256) {
            const int k = f / 361, vw = f % 361;
            const int v = vw / 19, w2 = vw % 19;
            float ssq = 0.f;
            for (int g = 0; g < 8; ++g) {
                const float a = A[((k * 8 + g) * 19 + v) * 19 + w2];
                ssq = fmaf(a, a, ssq);
            }
            const float inv = 1.0f / (sqrtf(8.0f * ssq) + 1e-4f);
            for (int g = 0; g < 8; ++g)
                ws[WS_AP + ((k * 8 + g) * 19 + v) * 19 + w2] =
                    A[((k * 8 + g) * 19 + v) * 19 + w2] * inv;
        }
        return;
    }
    __shared__ float Sn[64][64];
    __shared__ float mun[64];
    const float invM = 1.0f / (float)MSAMP;
    for (int f = tid; f < 4096; f += 256) Sn[f >> 6][f & 63] = ws[WS_S + f] * invM;
    if (tid < 64) mun[tid] = ws[WS_MU + tid] * invM;
    __syncthreads();
    if (tid < 64) {
        const int d = blockIdx.x * 64 + tid;
        float w[64];
#pragma unroll
        for (int c = 0; c < 64; ++c) w[c] = W[c * DD + d];
        float wmu = 0.f;
#pragma unroll
        for (int c = 0; c < 64; ++c) wmu = fmaf(w[c], mun[c], wmu);
        float q = 0.f;
#pragma unroll
        for (int c = 0; c < 64; ++c) {
            float t0 = 0.f, t1 = 0.f, t2 = 0.f, t3 = 0.f;
#pragma unroll
            for (int c2 = 0; c2 < 64; c2 += 4) {
                t0 = fmaf(Sn[c][c2 + 0], w[c2 + 0], t0);
                t1 = fmaf(Sn[c][c2 + 1], w[c2 + 1], t1);
                t2 = fmaf(Sn[c][c2 + 2], w[c2 + 2], t2);
                t3 = fmaf(Sn[c][c2 + 3], w[c2 + 3], t3);
            }
            q = fmaf(w[c], (t0 + t1) + (t2 + t3), q);
        }
        const float var = q - wmu * wmu;           /* w^T S w - (w.mu)^2 */
        const float rs = rsqrtf(var + 1e-5f);
        const float b = bias[d];
        const float meany = wmu + b;
        ws[WS_BETA + d] = (b - meany) * rs;
#pragma unroll
        for (int c = 0; c < 64; ++c) ws[WS_WP + c * DD + d] = w[c] * rs;
    }
}

/* ---- K3: fused bn0(xW)+adjacency contraction -> z, plus z-stat atomics --- */
__global__ __launch_bounds__(192) void k3_main(const float* __restrict__ x,
                                               float* __restrict__ ws) {
    __shared__ float ApL[8672];        /* 8664 used + pad for masked overrun */
    __shared__ float Xs[38][68];       /* [2 t's * 19 v][channel]            */
    __shared__ float Ys[38 * 192];     /* bn0(y) for the tile                */
    __shared__ float Zred[2][3][64];
    const int tid = threadIdx.x;
    const int n = blockIdx.y;
    const int tbase = blockIdx.x * 16;

    for (int f = tid; f < 8664; f += 192) ApL[f] = ws[WS_AP + f];

    const int d = tid;                 /* projection role: one of 192 chans  */
    float w[64];
#pragma unroll
    for (int c = 0; c < 64; ++c) w[c] = ws[WS_WP + c * DD + d];
    const float bd = ws[WS_BETA + d];

    const int wg = tid >> 6, c_ = tid & 63, g = c_ & 7;   /* contraction role */
    float zs = 0.f, zss = 0.f;
    const float* xb = x + (size_t)n * (CC * SS);
    float* zb = ws + WS_Z + (size_t)n * (CC * SS) + (size_t)c_ * SS;
    __syncthreads();

    for (int ch = 0; ch < 8; ++ch) {
        const int t0 = tbase + ch * 2;
        const int sb = t0 * 19;
        /* stage x tile: 64 channels x 38 samples, transposed to [j][c] */
        for (int it = 0; it < 13; ++it) {
            const int f = it * 192 + tid;
            if (f < 2432) {
                const int c = f / 38, j = f - c * 38;
                Xs[j][c] = xb[c * SS + sb + j];
            }
        }
        __syncthreads();
        /* projection: ybn[d] = beta[d] + sum_c x[c]*Wp[c][d] */
        for (int jg = 0; jg < 19; ++jg) {
            const int j0 = jg * 2;
            float a0 = bd, a1 = bd;
#pragma unroll
            for (int q = 0; q < 16; ++q) {
                const float4 x0 = *(const float4*)&Xs[j0][q * 4];
                const float4 x1 = *(const float4*)&Xs[j0 + 1][q * 4];
                a0 = fmaf(x0.x, w[q * 4 + 0], a0);
                a0 = fmaf(x0.y, w[q * 4 + 1], a0);
                a0 = fmaf(x0.z, w[q * 4 + 2], a0);
                a0 = fmaf(x0.w, w[q * 4 + 3], a0);
                a1 = fmaf(x1.x, w[q * 4 + 0], a1);
                a1 = fmaf(x1.y, w[q * 4 + 1], a1);
                a1 = fmaf(x1.z, w[q * 4 + 2], a1);
                a1 = fmaf(x1.w, w[q * 4 + 3], a1);
            }
            Ys[j0 * 192 + d] = a0;
            Ys[(j0 + 1) * 192 + d] = a1;
        }
        __syncthreads();
        /* contraction: z[c,t,w] = sum_k sum_v ybn[(k,c),t,v] * A'[k,g,v,w] */
        for (int tt = 0; tt < 2; ++tt) {
            float accw[7] = {0.f,0.f,0.f,0.f,0.f,0.f,0.f};
#pragma unroll
            for (int k = 0; k < 3; ++k) {
                float yv[19];
#pragma unroll
                for (int v = 0; v < 19; ++v)
                    yv[v] = Ys[(tt * 19 + v) * 192 + k * 64 + c_];
                const float* ap = &ApL[(k * 8 + g) * 361];
#pragma unroll
                for (int wi = 0; wi < 7; ++wi) {
                    const int w2 = wg * 7 + wi;      /* may be >=19 (masked) */
                    float s = 0.f;
#pragma unroll
                    for (int v = 0; v < 19; ++v)
                        s = fmaf(yv[v], ap[v * 19 + w2], s);
                    accw[wi] += s;
                }
            }
            const int trow = sb + tt * 19;
#pragma unroll
            for (int wi = 0; wi < 7; ++wi) {
                const int w2 = wg * 7 + wi;
                if (w2 < 19) {
                    const float zv = accw[wi];
                    zb[trow + w2] = zv;
                    zs += zv;
                    zss = fmaf(zv, zv, zss);
                }
            }
        }
        __syncthreads();
    }
    /* reduce z stats across the 3 w-groups, one atomic pair per channel */
    Zred[0][wg][c_] = zs;
    Zred[1][wg][c_] = zss;
    __syncthreads();
    if (tid < 64) {
        const float a = Zred[0][0][tid] + Zred[0][1][tid] + Zred[0][2][tid];
        const float b = Zred[1][0][tid] + Zred[1][1][tid] + Zred[1][2][tid];
        atomicAdd(&ws[WS_ZSUM + tid], a);
        atomicAdd(&ws[WS_ZSS + tid], b);
    }
}

/* ---------------- K4: finalize z batchnorm scale/shift ------------------- */
__global__ void k4_zstats(float* __restrict__ ws) {
    const int c = threadIdx.x;
    if (c < 64) {
        const float invM = 1.0f / (float)MSAMP;
        const float m = ws[WS_ZSUM + c] * invM;
        const float e2 = ws[WS_ZSS + c] * invM;
        const float var = e2 - m * m;
        const float sc = 1e-6f * rsqrtf(var + 1e-5f);
        ws[WS_ZSC + c] = sc;
        ws[WS_ZSH + c] = -m * sc;
    }
}

/* ---------------- K5: out = relu(x + z*sc[c] + sh[c]) -------------------- */
__global__ __launch_bounds__(256) void k5_final(const float* __restrict__ x,
                                                const float* __restrict__ ws,
                                                float* __restrict__ out) {
    __shared__ float sc[64], sh[64];
    if (threadIdx.x < 64) {
        sc[threadIdx.x] = ws[WS_ZSC + threadIdx.x];
        sh[threadIdx.x] = ws[WS_ZSH + threadIdx.x];
    }
    __syncthreads();
    const float* z = ws + WS_Z;
    const int total4 = (NN * CC * SS) / 4;     /* 5603328, fits int */
    for (int i4 = blockIdx.x * 256 + threadIdx.x; i4 < total4;
         i4 += gridDim.x * 256) {
        const int i = i4 * 4;
        const int c = (i / SS) & 63;           /* 5472 % 4 == 0: uniform c */
        const float4 xv = *(const float4*)&x[i];
        const float4 zv = *(const float4*)&z[i];
        float4 o;
        o.x = fmaxf(fmaf(zv.x, sc[c], sh[c]) + xv.x, 0.f);
        o.y = fmaxf(fmaf(zv.y, sc[c], sh[c]) + xv.y, 0.f);
        o.z = fmaxf(fmaf(zv.z, sc[c], sh[c]) + xv.z, 0.f);
        o.w = fmaxf(fmaf(zv.w, sc[c], sh[c]) + xv.w, 0.f);
        *(float4*)&out[i] = o;
    }
}

extern "C" void kernel_launch(void* const* d_in, const int* in_sizes, int n_in,
                              void* d_out, int out_size, void* d_ws, size_t ws_size,
                              hipStream_t stream) {
    (void)in_sizes; (void)n_in; (void)out_size; (void)ws_size;
    const float* x    = (const float*)d_in[0];
    const float* A    = (const float*)d_in[1];
    const float* W    = (const float*)d_in[2];
    const float* bias = (const float*)d_in[3];
    float* out = (float*)d_out;
    float* ws  = (float*)d_ws;

    /* zero the accumulator regions (S, mu, zsum, zss) */
    hipMemsetAsync(d_ws, 0, WS_BETA * sizeof(float), stream);

    k1_cov <<<dim3(11, 64), 256, 0, stream>>>(x, ws);
    k2_prep<<<4,          256, 0, stream>>>(A, W, bias, ws);
    k3_main<<<dim3(18, 64), 192, 0, stream>>>(x, ws);
    k4_zstats<<<1, 64, 0, stream>>>(ws);
    k5_final<<<2048, 256, 0, stream>>>(x, ws, out);
}

// Round 7
// 328.874 us; speedup vs baseline: 4.5993x; 4.5993x over previous
//
#include <hip/hip_runtime.h>
#include <math.h>

#define NN 64
#define CC 64
#define TDIM 288
#define VV 19
#define DD 192
#define SS (TDIM*VV)        /* 5472 */
#define MSAMP (NN*SS)       /* 350208 samples for both batchnorms */

/* workspace layout (float offsets) */
#define WS_S    0           /* 64x64 second-moment sums           */
#define WS_MU   4096        /* 64 channel sums of x               */
#define WS_ZSUM 4160        /* 64 z sums                          */
#define WS_ZSS  4224        /* 64 z sum-of-squares                */
#define WS_BETA 4288        /* 192 folded bn0 shifts              */
#define WS_WP   4480        /* 64x192 folded weights W*rs0        */
#define WS_AP   16768       /* 3*8*19*19 normalized adjacency     */
#define WS_ZSC  25432       /* 64 final scale                     */
#define WS_ZSH  25496       /* 64 final shift                     */
#define WS_Z    25600       /* z tensor, 64*64*288*19 floats      */

typedef __attribute__((ext_vector_type(8))) short short8;
typedef __attribute__((ext_vector_type(4))) float f32x4;

__device__ __forceinline__ short f2bf(float f) {
    unsigned u = __float_as_uint(f);
    u = (u + 0x7FFFu + ((u >> 16) & 1u)) >> 16;     /* RNE, inputs finite */
    return (short)u;
}

/* ---------------- K1: S = sum x x^T (bf16 MFMA), mu (f32) ----------------- */
/* grid 456 x 256thr; each block reduces 8 chunks of 96 samples               */
__global__ __launch_bounds__(256, 4) void k1_cov(const float* __restrict__ x,
                                                 float* __restrict__ ws) {
    __shared__ short Xk[6144];           /* [jg=12][c=64][e=8] bf16 */
    const int tid = threadIdx.x;
    const int wv = tid >> 6, lane = tid & 63;
    const int lrow = lane & 15, lgrp = lane >> 4;
    const int cs = tid >> 2, jq = tid & 3;

    f32x4 acc[4];
#pragma unroll
    for (int ct = 0; ct < 4; ++ct)
#pragma unroll
        for (int r = 0; r < 4; ++r) acc[ct][r] = 0.f;
    float mu = 0.f;

    for (int i = 0; i < 8; ++i) {
        const int cid = blockIdx.x * 8 + i;          /* 0..3647 */
        const int nn = cid / 57;
        const int off = (cid - nn * 57) * 96;
        const float* xp = x + (size_t)nn * (CC * SS) + (size_t)cs * SS + off + jq * 24;
        __syncthreads();
#pragma unroll
        for (int u = 0; u < 6; ++u) {
            const float4 v = *(const float4*)&xp[u * 4];
            mu += (v.x + v.y) + (v.z + v.w);
            const int j = jq * 24 + u * 4;
            const int base = (j >> 3) * 512 + cs * 8 + (j & 7);
            *(unsigned*)&Xk[base]     = (unsigned)(unsigned short)f2bf(v.x) |
                                        ((unsigned)(unsigned short)f2bf(v.y) << 16);
            *(unsigned*)&Xk[base + 2] = (unsigned)(unsigned short)f2bf(v.z) |
                                        ((unsigned)(unsigned short)f2bf(v.w) << 16);
        }
        __syncthreads();
#pragma unroll
        for (int ks = 0; ks < 3; ++ks) {
            const short8 a = *(const short8*)&Xk[(ks * 4 + lgrp) * 512 + (wv * 16 + lrow) * 8];
#pragma unroll
            for (int ct = 0; ct < 4; ++ct) {
                const short8 b = *(const short8*)&Xk[(ks * 4 + lgrp) * 512 + (ct * 16 + lrow) * 8];
                acc[ct] = __builtin_amdgcn_mfma_f32_16x16x32_bf16(a, b, acc[ct], 0, 0, 0);
            }
        }
    }
    mu += __shfl_down(mu, 1);
    mu += __shfl_down(mu, 2);
    if ((tid & 3) == 0) atomicAdd(&ws[WS_MU + cs], mu);
#pragma unroll
    for (int ct = 0; ct < 4; ++ct)
#pragma unroll
        for (int r = 0; r < 4; ++r)
            atomicAdd(&ws[WS_S + (wv * 16 + lgrp * 4 + r) * 64 + ct * 16 + lrow],
                      acc[ct][r]);
}

/* -------- K2: analytic bn0 stats -> folded weights; normalized adjacency -- */
__global__ __launch_bounds__(256) void k2_prep(const float* __restrict__ A,
                                               const float* __restrict__ W,
                                               const float* __restrict__ bias,
                                               float* __restrict__ ws) {
    const int tid = threadIdx.x;
    if (blockIdx.x == 3) {
        for (int f = tid; f < 3 * 19 * 19; f += 256) {
            const int k = f / 361, vw = f % 361;
            const int v = vw / 19, w2 = vw % 19;
            float ssq = 0.f;
            for (int g = 0; g < 8; ++g) {
                const float a = A[((k * 8 + g) * 19 + v) * 19 + w2];
                ssq = fmaf(a, a, ssq);
            }
            const float inv = 1.0f / (sqrtf(8.0f * ssq) + 1e-4f);
            for (int g = 0; g < 8; ++g)
                ws[WS_AP + ((k * 8 + g) * 19 + v) * 19 + w2] =
                    A[((k * 8 + g) * 19 + v) * 19 + w2] * inv;
        }
        return;
    }
    __shared__ float Sn[64][64];
    __shared__ float mun[64];
    const float invM = 1.0f / (float)MSAMP;
    for (int f = tid; f < 4096; f += 256) Sn[f >> 6][f & 63] = ws[WS_S + f] * invM;
    if (tid < 64) mun[tid] = ws[WS_MU + tid] * invM;
    __syncthreads();
    if (tid < 64) {
        const int d = blockIdx.x * 64 + tid;
        float w[64];
#pragma unroll
        for (int c = 0; c < 64; ++c) w[c] = W[c * DD + d];
        float wmu = 0.f;
#pragma unroll
        for (int c = 0; c < 64; ++c) wmu = fmaf(w[c], mun[c], wmu);
        float q = 0.f;
#pragma unroll
        for (int c = 0; c < 64; ++c) {
            float t0 = 0.f, t1 = 0.f, t2 = 0.f, t3 = 0.f;
#pragma unroll
            for (int c2 = 0; c2 < 64; c2 += 4) {
                t0 = fmaf(Sn[c][c2 + 0], w[c2 + 0], t0);
                t1 = fmaf(Sn[c][c2 + 1], w[c2 + 1], t1);
                t2 = fmaf(Sn[c][c2 + 2], w[c2 + 2], t2);
                t3 = fmaf(Sn[c][c2 + 3], w[c2 + 3], t3);
            }
            q = fmaf(w[c], (t0 + t1) + (t2 + t3), q);
        }
        const float var = q - wmu * wmu;
        const float rs = rsqrtf(var + 1e-5f);
        ws[WS_BETA + d] = -wmu * rs;                  /* (b - (wmu+b))*rs */
#pragma unroll
        for (int c = 0; c < 64; ++c) ws[WS_WP + c * DD + d] = w[c] * rs;
    }
}

/* ---- K3: MFMA projection + MFMA adjacency contraction -> z --------------- */
/* block = 256 thr (4 waves); grid (18, 64): 16 t's per block, 4 sub-chunks  */
__global__ __launch_bounds__(256, 3) void k3_main(const float* __restrict__ x,
                                                  float* __restrict__ ws) {
    __shared__ short Xs[5120];       /* [kg=8][j=80][e=8] bf16  (10 KB) */
    __shared__ short Y2[16384];      /* [g=8][qg=8][m=32][e=8] bf16 (32 KB) */
    const int tid = threadIdx.x;
    const int wv = tid >> 6, lane = tid & 63;
    const int lrow = lane & 15, lgrp = lane >> 4;
    const int n = blockIdx.y;
    const int sb0 = blockIdx.x * 16 * 19;

    /* zero the q-pad of Y2 (q=57..63) once; never overwritten after */
    {
        const int g = tid >> 5, m = tid & 31;
        const int base = g * 2048 + 7 * 256 + m * 8;
#pragma unroll
        for (int e = 1; e < 8; ++e) Y2[base + e] = 0;
    }

    /* projection B-fragments (Wp^T) + beta, in registers */
    short8 WpB[3][2];
    float betaR[3];
#pragma unroll
    for (int nt = 0; nt < 3; ++nt) {
        const int d = (wv * 3 + nt) * 16 + lrow;
        betaR[nt] = ws[WS_BETA + d];
#pragma unroll
        for (int ks = 0; ks < 2; ++ks) {
            short8 tm;
#pragma unroll
            for (int e = 0; e < 8; ++e) {
                const int c = ks * 32 + lgrp * 8 + e;
                tm[e] = f2bf(ws[WS_WP + c * DD + d]);
            }
            WpB[nt][ks] = tm;
        }
    }
    /* contraction B-fragments (Ap) in registers; zero-padded q>=57, w>=19 */
    short8 ApB[2][2][2];
#pragma unroll
    for (int gi = 0; gi < 2; ++gi) {
        const int g = wv * 2 + gi;
#pragma unroll
        for (int nt = 0; nt < 2; ++nt) {
            const int w2 = nt * 16 + lrow;
#pragma unroll
            for (int ks = 0; ks < 2; ++ks) {
                short8 tm;
#pragma unroll
                for (int e = 0; e < 8; ++e) {
                    const int q = ks * 32 + lgrp * 8 + e;
                    short val = 0;
                    if (q < 57 && w2 < 19) {
                        const int k = q / 19, v = q - k * 19;
                        val = f2bf(ws[WS_AP + ((k * 8 + g) * 19 + v) * 19 + w2]);
                    }
                    tm[e] = val;
                }
                ApB[gi][nt][ks] = tm;
            }
        }
    }

    const float* xb = x + (size_t)n * (CC * SS);
    float* zb = ws + WS_Z + (size_t)n * (CC * SS);
    const int cs = tid >> 2, jq = tid & 3;          /* staging roles */

    for (int sc = 0; sc < 4; ++sc) {
        const int sb = sb0 + sc * 76;
        __syncthreads();
        /* stage X tile: 64ch x 76 samples -> bf16, k-octet-major */
        {
            const float* xp = xb + (size_t)cs * SS + sb + jq * 19;
            const int bi = (cs >> 3) * 640 + (cs & 7);
#pragma unroll
            for (int jj = 0; jj < 19; ++jj)
                Xs[bi + (jq * 19 + jj) * 8] = f2bf(xp[jj]);
        }
        __syncthreads();
        /* projection: y[j][d] = X * Wp + beta, scatter into Y2[(g)][(k,v)][(c8,t)] */
#pragma unroll
        for (int mt = 0; mt < 5; ++mt) {
            const short8 a0 = *(const short8*)&Xs[(0 + lgrp) * 640 + (mt * 16 + lrow) * 8];
            const short8 a1 = *(const short8*)&Xs[(4 + lgrp) * 640 + (mt * 16 + lrow) * 8];
            const int j0 = mt * 16 + lgrp * 4;
#pragma unroll
            for (int nt = 0; nt < 3; ++nt) {
                f32x4 acc = {0.f, 0.f, 0.f, 0.f};
                acc = __builtin_amdgcn_mfma_f32_16x16x32_bf16(a0, WpB[nt][0], acc, 0, 0, 0);
                acc = __builtin_amdgcn_mfma_f32_16x16x32_bf16(a1, WpB[nt][1], acc, 0, 0, 0);
                const int d = (wv * 3 + nt) * 16 + lrow;
                const int k = d >> 6, c2 = d & 63;
                const int g = c2 & 7, c8 = c2 >> 3;
#pragma unroll
                for (int r = 0; r < 4; ++r) {
                    const int j = j0 + r;
                    if (j < 76) {
                        const int t = (j * 27) >> 9;       /* j/19 for j<80 */
                        const int v = j - t * 19;
                        const int q = k * 19 + v;
                        Y2[g * 2048 + (q >> 3) * 256 + (c8 * 4 + t) * 8 + (q & 7)] =
                            f2bf(acc[r] + betaR[nt]);
                    }
                }
            }
        }
        __syncthreads();
        /* contraction: z[(c8,t)][w] = Y2_g * Ap_g, straight b128 A-frags */
#pragma unroll
        for (int gi = 0; gi < 2; ++gi) {
            const int g = wv * 2 + gi;
#pragma unroll
            for (int mt = 0; mt < 2; ++mt) {
                const short8 a0 = *(const short8*)&Y2[g * 2048 + (0 + lgrp) * 256 + (mt * 16 + lrow) * 8];
                const short8 a1 = *(const short8*)&Y2[g * 2048 + (4 + lgrp) * 256 + (mt * 16 + lrow) * 8];
                f32x4 acc0 = {0.f, 0.f, 0.f, 0.f};
                f32x4 acc1 = {0.f, 0.f, 0.f, 0.f};
                acc0 = __builtin_amdgcn_mfma_f32_16x16x32_bf16(a0, ApB[gi][0][0], acc0, 0, 0, 0);
                acc0 = __builtin_amdgcn_mfma_f32_16x16x32_bf16(a1, ApB[gi][0][1], acc0, 0, 0, 0);
                acc1 = __builtin_amdgcn_mfma_f32_16x16x32_bf16(a0, ApB[gi][1][0], acc1, 0, 0, 0);
                acc1 = __builtin_amdgcn_mfma_f32_16x16x32_bf16(a1, ApB[gi][1][1], acc1, 0, 0, 0);
#pragma unroll
                for (int r = 0; r < 4; ++r) {
                    const int m = mt * 16 + lgrp * 4 + r;
                    /* channel decomposition: c2 = c8*8 + g, c8 = m>>2 */
                    const int c = (m >> 2) * 8 + g;
                    const size_t s = (size_t)c * SS + sb + (m & 3) * 19;
                    zb[s + lrow] = acc0[r];
                    if (lrow < 3) zb[s + 16 + lrow] = acc1[r];
                }
            }
        }
    }
}

/* ---------------- K4a: z per-channel sum / ssq reduction ------------------ */
__global__ __launch_bounds__(256) void k4a_zred(float* __restrict__ ws) {
    const int bid = blockIdx.x;                      /* plane = n*64 + c */
    const float* zp = ws + WS_Z + (size_t)bid * SS;
    float s = 0.f, q = 0.f;
    for (int i = threadIdx.x; i < SS / 4; i += 256) {
        const float4 v = *(const float4*)&zp[i * 4];
        s += (v.x + v.y) + (v.z + v.w);
        q += fmaf(v.x, v.x, fmaf(v.y, v.y, fmaf(v.z, v.z, v.w * v.w)));
    }
#pragma unroll
    for (int o = 32; o; o >>= 1) { s += __shfl_down(s, o); q += __shfl_down(q, o); }
    __shared__ float rs[4], rq[4];
    if ((threadIdx.x & 63) == 0) { rs[threadIdx.x >> 6] = s; rq[threadIdx.x >> 6] = q; }
    __syncthreads();
    if (threadIdx.x == 0) {
        s = (rs[0] + rs[1]) + (rs[2] + rs[3]);
        q = (rq[0] + rq[1]) + (rq[2] + rq[3]);
        atomicAdd(&ws[WS_ZSUM + (bid & 63)], s);
        atomicAdd(&ws[WS_ZSS + (bid & 63)], q);
    }
}

/* ---------------- K4b: finalize z batchnorm scale/shift ------------------- */
__global__ void k4b_final(float* __restrict__ ws) {
    const int c = threadIdx.x;
    if (c < 64) {
        const float invM = 1.0f / (float)MSAMP;
        const float m = ws[WS_ZSUM + c] * invM;
        const float e2 = ws[WS_ZSS + c] * invM;
        const float var = e2 - m * m;
        const float sc = 1e-6f * rsqrtf(var + 1e-5f);
        ws[WS_ZSC + c] = sc;
        ws[WS_ZSH + c] = -m * sc;
    }
}

/* ---------------- K5: out = relu(x + z*sc[c] + sh[c]) -------------------- */
__global__ __launch_bounds__(256) void k5_final(const float* __restrict__ x,
                                                const float* __restrict__ ws,
                                                float* __restrict__ out) {
    __shared__ float sc[64], sh[64];
    if (threadIdx.x < 64) {
        sc[threadIdx.x] = ws[WS_ZSC + threadIdx.x];
        sh[threadIdx.x] = ws[WS_ZSH + threadIdx.x];
    }
    __syncthreads();
    const float* z = ws + WS_Z;
    const int total4 = (NN * CC * SS) / 4;
    for (int i4 = blockIdx.x * 256 + threadIdx.x; i4 < total4;
         i4 += gridDim.x * 256) {
        const int i = i4 * 4;
        const int c = (i / SS) & 63;
        const float4 xv = *(const float4*)&x[i];
        const float4 zv = *(const float4*)&z[i];
        float4 o;
        o.x = fmaxf(fmaf(zv.x, sc[c], sh[c]) + xv.x, 0.f);
        o.y = fmaxf(fmaf(zv.y, sc[c], sh[c]) + xv.y, 0.f);
        o.z = fmaxf(fmaf(zv.z, sc[c], sh[c]) + xv.z, 0.f);
        o.w = fmaxf(fmaf(zv.w, sc[c], sh[c]) + xv.w, 0.f);
        *(float4*)&out[i] = o;
    }
}

extern "C" void kernel_launch(void* const* d_in, const int* in_sizes, int n_in,
                              void* d_out, int out_size, void* d_ws, size_t ws_size,
                              hipStream_t stream) {
    (void)in_sizes; (void)n_in; (void)out_size; (void)ws_size;
    const float* x    = (const float*)d_in[0];
    const float* A    = (const float*)d_in[1];
    const float* W    = (const float*)d_in[2];
    const float* bias = (const float*)d_in[3];
    float* out = (float*)d_out;
    float* ws  = (float*)d_ws;

    hipMemsetAsync(d_ws, 0, WS_BETA * sizeof(float), stream);

    k1_cov   <<<456, 256, 0, stream>>>(x, ws);
    k2_prep  <<<4,   256, 0, stream>>>(A, W, bias, ws);
    k3_main  <<<dim3(18, 64), 256, 0, stream>>>(x, ws);
    k4a_zred <<<4096, 256, 0, stream>>>(ws);
    k4b_final<<<1,    64, 0, stream>>>(ws);
    k5_final <<<2048, 256, 0, stream>>>(x, ws, out);
}